// Round 1
// baseline (116.735 us; speedup 1.0000x reference)
//
#include <hip/hip_runtime.h>
#include <cstdint>
#include <cstddef>

// ---------------- problem constants ----------------
#define NB    32          // batch
#define CI    128         // in channels
#define CO    256         // out channels
#define HW_   56          // spatial
#define HP    58          // padded spatial
#define KTOT  1152        // 128*9 reduction
#define MTOT  (NB * HW_ * HW_)   // 100352 output pixels

static constexpr size_t XP_ELEMS = (size_t)NB * HP * HP * CI;   // 13,776,896
static constexpr size_t WT_ELEMS = (size_t)CO * KTOT;           // 294,912
static constexpr size_t XP_BYTES = XP_ELEMS * 2;
static constexpr size_t WT_BYTES = WT_ELEMS * 2;

typedef __attribute__((ext_vector_type(8))) short bf16x8;
typedef __attribute__((ext_vector_type(4))) float f32x4;

__device__ __forceinline__ short f32_to_bf16(float f) {
  uint32_t u = __float_as_uint(f);
  uint32_t r = (u + 0x7FFFu + ((u >> 16) & 1u)) >> 16;
  return (short)r;
}

typedef __attribute__((address_space(3))) void       lds_void;
typedef const __attribute__((address_space(1))) void gbl_void;

__device__ __forceinline__ void gload16(const void* g, void* l) {
  // dest = wave-uniform LDS base; HW writes lane's 16B at base + lane*16
  __builtin_amdgcn_global_load_lds((gbl_void*)g, (lds_void*)l, 16, 0, 0);
}

// ---------------- pre-pass: x NCHW f32 -> padded NHWC bf16 ----------------
__global__ void pad_convert(const float* __restrict__ x, short* __restrict__ xp) {
  __shared__ float lds[CI][57];  // 57 stride: odd -> conflict-free-ish
  const int blk = blockIdx.x;    // NB*HP
  const int hp  = blk % HP;
  const int nb  = blk / HP;
  const int tid = threadIdx.x;   // 256
  const bool interior = (hp >= 1 && hp <= HW_);
  if (interior) {
    const float* src = x + (size_t)nb * CI * HW_ * HW_ + (size_t)(hp - 1) * HW_;
    for (int t = tid; t < CI * HW_; t += 256) {
      int c = t / HW_, w = t % HW_;
      lds[c][w] = src[(size_t)c * HW_ * HW_ + w];
    }
  }
  __syncthreads();
  short* dst = xp + (size_t)(nb * HP + hp) * HP * CI;
  for (int t = tid; t < HP * CI; t += 256) {
    int wp = t >> 7, c = t & 127;
    float v = 0.f;
    if (interior && wp >= 1 && wp <= HW_) v = lds[c][wp - 1];
    dst[t] = f32_to_bf16(v);
  }
}

// ---------------- pre-pass: weight OIHW f32 -> [o][kh][kw][c] bf16 ----------------
__global__ void wt_convert(const float* __restrict__ wt, short* __restrict__ wbT) {
  int idx = blockIdx.x * 256 + threadIdx.x;       // WT_ELEMS total, exact
  int c  = idx & 127;
  int t  = idx >> 7;          // o*9 + kh*3 + kw
  int kw = t % 3;  int t2 = t / 3;
  int kh = t2 % 3; int o  = t2 / 3;
  wbT[idx] = f32_to_bf16(wt[(((size_t)o * CI + c) * 3 + kh) * 3 + kw]);
}

// ---------------- main: implicit GEMM, 128x128 tile, BK=32, 4 waves ----------------
__global__ __launch_bounds__(256) void conv_gemm(
    const short* __restrict__ xp, const short* __restrict__ wbT,
    const float* __restrict__ bias, float* __restrict__ out) {
  __shared__ __align__(16) short Asm[128 * 32];   // [m_local][k_local] bf16
  __shared__ __align__(16) short Bsm[128 * 32];   // [oc_local][k_local] bf16

  const int tid  = threadIdx.x;
  const int lane = tid & 63;
  const int wv   = tid >> 6;        // 0..3
  const int wm   = wv >> 1, wn = wv & 1;

  const int bid = blockIdx.x;       // 784*2
  const int nt  = bid & 1;          // oc tile
  const int mt  = bid >> 1;         // pixel tile

  const int srow = lane >> 2;       // staging row within 16-row chunk
  const int skp  = lane & 3;        // staging 16B piece (8 bf16)

  const short* aSrc[2];  const short* bSrc[2];
  short* aDst[2];        short* bDst[2];
#pragma unroll
  for (int q = 0; q < 2; ++q) {
    const int chunk = wv * 2 + q;             // 0..7
    const int mloc  = chunk * 16 + srow;
    const int m     = mt * 128 + mloc;        // < 100352 always
    const int nb    = m / 3136;
    const int hw    = m - nb * 3136;
    const int h     = hw / HW_, w = hw - (hw / HW_) * HW_;
    aSrc[q] = xp + (size_t)((nb * HP + h) * HP + w) * CI + skp * 8;
    aDst[q] = &Asm[chunk * 512];              // 1KB chunks
    bSrc[q] = wbT + (size_t)(nt * 128 + mloc) * KTOT + skp * 8;
    bDst[q] = &Bsm[chunk * 512];
  }

  f32x4 acc[4][4];
#pragma unroll
  for (int i = 0; i < 4; ++i)
#pragma unroll
    for (int j = 0; j < 4; ++j) acc[i][j] = {0.f, 0.f, 0.f, 0.f};

  const int frow = lane & 15;
  const int fkp  = (lane >> 4) * 8;
  const short* aFragBase = &Asm[(wm * 64 + frow) * 32 + fkp];
  const short* bFragBase = &Bsm[(wn * 64 + frow) * 32 + fkp];

  for (int kh = 0; kh < 3; ++kh) {
    for (int kw = 0; kw < 3; ++kw) {
      const int aoff = (kh * HP + kw) * CI;         // xp element offset for this tap
      const int kbase = (kh * 3 + kw) * CI;         // global k of this tap
      for (int cb = 0; cb < 4; ++cb) {
        const int k0 = kbase + cb * 32;
        // stage A,B tiles (4 x 1KB wave-chunks per wave)
        gload16(aSrc[0] + aoff + cb * 32, aDst[0]);
        gload16(aSrc[1] + aoff + cb * 32, aDst[1]);
        gload16(bSrc[0] + k0, bDst[0]);
        gload16(bSrc[1] + k0, bDst[1]);
        __syncthreads();    // drains vmcnt -> LDS tiles valid
        bf16x8 af[4], bf[4];
#pragma unroll
        for (int mi = 0; mi < 4; ++mi)
          af[mi] = *(const bf16x8*)(aFragBase + mi * 16 * 32);
#pragma unroll
        for (int ni = 0; ni < 4; ++ni)
          bf[ni] = *(const bf16x8*)(bFragBase + ni * 16 * 32);
#pragma unroll
        for (int mi = 0; mi < 4; ++mi)
#pragma unroll
          for (int ni = 0; ni < 4; ++ni)
            // swapped operands: D[r=oc][c=m] -> coalesced NCHW stores
            acc[mi][ni] = __builtin_amdgcn_mfma_f32_16x16x32_bf16(
                bf[ni], af[mi], acc[mi][ni], 0, 0, 0);
        __syncthreads();    // protect LDS before next stage
      }
    }
  }

  // epilogue: lane holds D rows oc=(lane>>4)*4+j, col m=lane&15 per 16x16 tile
  const int mBase  = mt * 128 + wm * 64 + frow;
  const int ocBase = nt * 128 + wn * 64 + (lane >> 4) * 4;
  float bv[4][4];
#pragma unroll
  for (int ni = 0; ni < 4; ++ni)
#pragma unroll
    for (int j = 0; j < 4; ++j) bv[ni][j] = bias[ocBase + ni * 16 + j];
#pragma unroll
  for (int mi = 0; mi < 4; ++mi) {
    const int m  = mBase + mi * 16;
    const int nb = m / 3136;
    const int hw = m - nb * 3136;
    float* op = out + (size_t)nb * CO * 3136 + hw;
#pragma unroll
    for (int ni = 0; ni < 4; ++ni) {
      const int oc = ocBase + ni * 16;
#pragma unroll
      for (int j = 0; j < 4; ++j)
        op[(size_t)(oc + j) * 3136] = acc[mi][ni][j] + bv[ni][j];
    }
  }
}

// ---------------- fallback (ws too small): naive direct conv ----------------
__global__ void conv_naive(const float* __restrict__ x, const float* __restrict__ wt,
                           const float* __restrict__ bias, float* __restrict__ out) {
  const int idx = blockIdx.x * 256 + threadIdx.x;
  if (idx >= NB * CO * 3136) return;
  const int w  = idx % HW_;
  const int h  = (idx / HW_) % HW_;
  const int oc = (idx / 3136) % CO;
  const int nb = idx / (3136 * CO);
  float s = bias[oc];
  for (int c = 0; c < CI; ++c)
    for (int kh = 0; kh < 3; ++kh) {
      const int ih = h + kh - 1;
      if (ih < 0 || ih >= HW_) continue;
      for (int kw = 0; kw < 3; ++kw) {
        const int iw = w + kw - 1;
        if (iw < 0 || iw >= HW_) continue;
        s += x[((size_t)(nb * CI + c) * HW_ + ih) * HW_ + iw] *
             wt[(((size_t)oc * CI + c) * 3 + kh) * 3 + kw];
      }
    }
  out[idx] = s;
}

extern "C" void kernel_launch(void* const* d_in, const int* in_sizes, int n_in,
                              void* d_out, int out_size, void* d_ws, size_t ws_size,
                              hipStream_t stream) {
  const float* x    = (const float*)d_in[0];
  const float* wt   = (const float*)d_in[1];
  const float* bias = (const float*)d_in[2];
  float* out        = (float*)d_out;

  if (ws_size < XP_BYTES + WT_BYTES) {
    // not enough scratch for bf16 staging -> slow but correct path
    conv_naive<<<(NB * CO * 3136 + 255) / 256, 256, 0, stream>>>(x, wt, bias, out);
    return;
  }

  short* xp  = (short*)d_ws;
  short* wbT = (short*)((char*)d_ws + XP_BYTES);

  pad_convert<<<NB * HP, 256, 0, stream>>>(x, xp);
  wt_convert<<<(int)(WT_ELEMS / 256), 256, 0, stream>>>(wt, wbT);
  conv_gemm<<<(MTOT / 128) * 2, 256, 0, stream>>>(xp, wbT, bias, out);
}

// Round 2
// 103.435 us; speedup vs baseline: 1.1286x; 1.1286x over previous
//
#include <hip/hip_runtime.h>
#include <cstdint>
#include <cstddef>

// ---------------- problem constants ----------------
#define NB    32          // batch
#define CI    128         // in channels
#define CO    256         // out channels
#define HW_   56          // spatial
#define HP    58          // padded spatial
#define KTOT  1152        // 128*9 reduction
#define NKT   36          // K-tiles of 32
#define MTOT  (NB * HW_ * HW_)   // 100352 output pixels

static constexpr size_t XP_ELEMS = (size_t)NB * HP * HP * CI;   // 13,776,896
static constexpr size_t WT_ELEMS = (size_t)CO * KTOT;           // 294,912
static constexpr size_t XP_BYTES = XP_ELEMS * 2;
static constexpr size_t WT_BYTES = WT_ELEMS * 2;

typedef __attribute__((ext_vector_type(8))) short bf16x8;
typedef __attribute__((ext_vector_type(4))) float f32x4;

__device__ __forceinline__ short f32_to_bf16(float f) {
  uint32_t u = __float_as_uint(f);
  uint32_t r = (u + 0x7FFFu + ((u >> 16) & 1u)) >> 16;
  return (short)r;
}

typedef __attribute__((address_space(3))) void       lds_void;
typedef const __attribute__((address_space(1))) void gbl_void;

__device__ __forceinline__ void gload16(const void* g, void* l) {
  // dest = wave-uniform LDS base; HW writes lane's 16B at base + lane*16
  __builtin_amdgcn_global_load_lds((gbl_void*)g, (lds_void*)l, 16, 0, 0);
}

// ---------------- pre-pass: x NCHW f32 -> padded NHWC bf16 ----------------
__global__ void pad_convert(const float* __restrict__ x, short* __restrict__ xp) {
  __shared__ float lds[CI][57];
  const int blk = blockIdx.x;    // NB*HP
  const int hp  = blk % HP;
  const int nb  = blk / HP;
  const int tid = threadIdx.x;   // 256
  const bool interior = (hp >= 1 && hp <= HW_);
  if (interior) {
    const float* src = x + (size_t)nb * CI * HW_ * HW_ + (size_t)(hp - 1) * HW_;
    for (int t = tid; t < CI * HW_; t += 256) {
      int c = t / HW_, w = t % HW_;
      lds[c][w] = src[(size_t)c * HW_ * HW_ + w];
    }
  }
  __syncthreads();
  short* dst = xp + (size_t)(nb * HP + hp) * HP * CI;
  for (int t = tid; t < HP * CI; t += 256) {
    int wp = t >> 7, c = t & 127;
    float v = 0.f;
    if (interior && wp >= 1 && wp <= HW_) v = lds[c][wp - 1];
    dst[t] = f32_to_bf16(v);
  }
}

// ---------------- pre-pass: weight OIHW f32 -> [o][kh][kw][c] bf16 ----------------
__global__ void wt_convert(const float* __restrict__ wt, short* __restrict__ wbT) {
  int idx = blockIdx.x * 256 + threadIdx.x;       // WT_ELEMS total, exact
  int c  = idx & 127;
  int t  = idx >> 7;          // o*9 + kh*3 + kw
  int kw = t % 3;  int t2 = t / 3;
  int kh = t2 % 3; int o  = t2 / 3;
  wbT[idx] = f32_to_bf16(wt[(((size_t)o * CI + c) * 3 + kh) * 3 + kw]);
}

// uniform scalar: byte offset into xp row for K-tile u (tap + channel-quarter)
__device__ __forceinline__ int tap_off_bytes(int u) {
  const int tap = u >> 2;            // 0..8
  const int cq  = u & 3;             // channel quarter (32 ch)
  const int kh  = tap / 3, kw = tap - kh * 3;
  return ((kh * HP + kw) * CI + cq * 32) * 2;
}

// ---------------- main: implicit GEMM, 128x256 tile, BK=32, 3-buffer pipeline ----
// 4 waves (WM=2 x WN=2); per-wave output 64 (m) x 128 (oc).
// LDS per buffer: A 128x32 bf16 (8KB) + B 256x32 bf16 (16KB) = 24KB; 3 bufs = 72KB
// -> 2 blocks/CU. Stage-ahead = 2 K-tiles; one barrier per K-tile; vmcnt(6)
// counted waits (vmcnt(0) only at the final boundary).
__global__ __launch_bounds__(256, 2) void conv_gemm(
    const short* __restrict__ xp, const short* __restrict__ wbT,
    const float* __restrict__ bias, float* __restrict__ out) {
  __shared__ __align__(16) char lds[3 * 24576];

  const int tid = threadIdx.x;
  const int l   = tid & 63;
  const int wv  = tid >> 6;         // 0..3
  const int wm  = wv >> 1, wn = wv & 1;
  const int mt  = blockIdx.x;       // 784 M-tiles, single N-tile

  // ---- per-lane staging source pointers (linear LDS dest, no swizzle at BK=32) ----
  // stage instr covers 64 rows: thread t -> row = (instr)*64 + wv*16 + (l>>2), piece = l&3
  const int piece = l & 3;                 // 16B piece within a 64B k-row
  const int srow  = wv * 16 + (l >> 2);    // 0..63 across the 4 waves
  const char* aP0; const char* aP1;
  {
    int r0 = srow, r1 = 64 + srow;
    int m0 = mt * 128 + r0, m1 = mt * 128 + r1;
    int nb0 = m0 / 3136, hw0 = m0 - nb0 * 3136, h0 = hw0 / HW_, w0 = hw0 - (hw0 / HW_) * HW_;
    int nb1 = m1 / 3136, hw1 = m1 - nb1 * 3136, h1 = hw1 / HW_, w1 = hw1 - (hw1 / HW_) * HW_;
    aP0 = (const char*)xp + ((size_t)((nb0 * HP + h0) * HP + w0) * CI + piece * 8) * 2;
    aP1 = (const char*)xp + ((size_t)((nb1 * HP + h1) * HP + w1) * CI + piece * 8) * 2;
  }
  const char* bP0 = (const char*)wbT + ((size_t)(  0 + srow) * KTOT + piece * 8) * 2;
  const char* bP1 = (const char*)wbT + ((size_t)( 64 + srow) * KTOT + piece * 8) * 2;
  const char* bP2 = (const char*)wbT + ((size_t)(128 + srow) * KTOT + piece * 8) * 2;
  const char* bP3 = (const char*)wbT + ((size_t)(192 + srow) * KTOT + piece * 8) * 2;

  // ---- per-lane LDS read offsets (frag: row = base + (l&15), kpiece = l>>4) ----
  const int raOff = (wm * 64  + (l & 15)) * 64 + (l >> 4) * 16;   // within A region (8KB)
  const int rbOff = (wn * 128 + (l & 15)) * 64 + (l >> 4) * 16;   // within B region (16KB)

  char* B0 = lds;
  char* B1 = lds + 24576;
  char* B2 = lds + 49152;

#define STAGE(U, BUF)                                                        \
  {                                                                          \
    const int aoff_ = tap_off_bytes(U);                                      \
    const int boff_ = (U) * 64;                                              \
    char* sA_ = (BUF) + wv * 1024;                                           \
    gload16(aP0 + aoff_, sA_);                                               \
    gload16(aP1 + aoff_, sA_ + 4096);                                        \
    char* sB_ = (BUF) + 8192 + wv * 1024;                                    \
    gload16(bP0 + boff_, sB_);                                               \
    gload16(bP1 + boff_, sB_ + 4096);                                        \
    gload16(bP2 + boff_, sB_ + 8192);                                        \
    gload16(bP3 + boff_, sB_ + 12288);                                       \
  }

  f32x4 acc[4][8];
#pragma unroll
  for (int g = 0; g < 4; ++g)
#pragma unroll
    for (int h = 0; h < 8; ++h) acc[g][h] = {0.f, 0.f, 0.f, 0.f};

  // ---- prologue: stage tiles 0,1; confirm tile 0 ----
  STAGE(0, B0)
  STAGE(1, B1)
  asm volatile("s_waitcnt vmcnt(6)" ::: "memory");
  __builtin_amdgcn_s_barrier();
  __builtin_amdgcn_sched_barrier(0);

#define TILE_BODY(V, CUR, STG)                                               \
  {                                                                          \
    const int v_ = (V);                                                      \
    if (v_ + 2 < NKT) STAGE(v_ + 2, STG)                                     \
    bf16x8 af[4], bf[8];                                                     \
    _Pragma("unroll") for (int g = 0; g < 4; ++g)                            \
        af[g] = *(const bf16x8*)((CUR) + raOff + g * 1024);                  \
    _Pragma("unroll") for (int h = 0; h < 8; ++h)                            \
        bf[h] = *(const bf16x8*)((CUR) + 8192 + rbOff + h * 1024);           \
    __builtin_amdgcn_s_setprio(1);                                           \
    _Pragma("unroll") for (int g = 0; g < 4; ++g)                            \
      _Pragma("unroll") for (int h = 0; h < 8; ++h)                          \
        acc[g][h] = __builtin_amdgcn_mfma_f32_16x16x32_bf16(                 \
            bf[h], af[g], acc[g][h], 0, 0, 0);                               \
    __builtin_amdgcn_s_setprio(0);                                           \
    if (v_ < NKT - 1) {                                                      \
      if (v_ == NKT - 2) { asm volatile("s_waitcnt vmcnt(0)" ::: "memory"); }\
      else               { asm volatile("s_waitcnt vmcnt(6)" ::: "memory"); }\
      __builtin_amdgcn_s_barrier();                                          \
      __builtin_amdgcn_sched_barrier(0);                                     \
    }                                                                        \
  }

  for (int v3 = 0; v3 < NKT; v3 += 3) {
    TILE_BODY(v3 + 0, B0, B2)   // tile v reads buf v%3, stages v+2 into (v+2)%3
    TILE_BODY(v3 + 1, B1, B0)
    TILE_BODY(v3 + 2, B2, B1)
  }

  // ---- epilogue: D rows = oc, cols = m (swapped operands) -> coalesced stores ----
  const int mBase = mt * 128 + wm * 64 + (l & 15);
  const int ocB   = wn * 128 + (l >> 4) * 4;
#pragma unroll
  for (int g = 0; g < 4; ++g) {
    const int m  = mBase + g * 16;
    const int nb = m / 3136;
    const int hw = m - nb * 3136;
    float* op = out + (size_t)nb * CO * 3136 + hw;
#pragma unroll
    for (int h = 0; h < 8; ++h) {
      const int oc = ocB + h * 16;
#pragma unroll
      for (int j = 0; j < 4; ++j)
        op[(size_t)(oc + j) * 3136] = acc[g][h][j] + bias[oc + j];
    }
  }
#undef TILE_BODY
#undef STAGE
}

// ---------------- fallback (ws too small): naive direct conv ----------------
__global__ void conv_naive(const float* __restrict__ x, const float* __restrict__ wt,
                           const float* __restrict__ bias, float* __restrict__ out) {
  const int idx = blockIdx.x * 256 + threadIdx.x;
  if (idx >= NB * CO * 3136) return;
  const int w  = idx % HW_;
  const int h  = (idx / HW_) % HW_;
  const int oc = (idx / 3136) % CO;
  const int nb = idx / (3136 * CO);
  float s = bias[oc];
  for (int c = 0; c < CI; ++c)
    for (int kh = 0; kh < 3; ++kh) {
      const int ih = h + kh - 1;
      if (ih < 0 || ih >= HW_) continue;
      for (int kw = 0; kw < 3; ++kw) {
        const int iw = w + kw - 1;
        if (iw < 0 || iw >= HW_) continue;
        s += x[((size_t)(nb * CI + c) * HW_ + ih) * HW_ + iw] *
             wt[(((size_t)oc * CI + c) * 3 + kh) * 3 + kw];
      }
    }
  out[idx] = s;
}

extern "C" void kernel_launch(void* const* d_in, const int* in_sizes, int n_in,
                              void* d_out, int out_size, void* d_ws, size_t ws_size,
                              hipStream_t stream) {
  const float* x    = (const float*)d_in[0];
  const float* wt   = (const float*)d_in[1];
  const float* bias = (const float*)d_in[2];
  float* out        = (float*)d_out;

  if (ws_size < XP_BYTES + WT_BYTES) {
    conv_naive<<<(NB * CO * 3136 + 255) / 256, 256, 0, stream>>>(x, wt, bias, out);
    return;
  }

  short* xp  = (short*)d_ws;
  short* wbT = (short*)((char*)d_ws + XP_BYTES);

  pad_convert<<<NB * HP, 256, 0, stream>>>(x, xp);
  wt_convert<<<(int)(WT_ELEMS / 256), 256, 0, stream>>>(wt, wbT);
  conv_gemm<<<MTOT / 128, 256, 0, stream>>>(xp, wbT, bias, out);
}

// Round 3
// 97.022 us; speedup vs baseline: 1.2032x; 1.0661x over previous
//
#include <hip/hip_runtime.h>
#include <cstdint>
#include <cstddef>

// ---------------- problem constants ----------------
#define NB    32          // batch
#define CI    128         // in channels
#define CO    256         // out channels
#define HW_   56          // spatial
#define HP    58          // padded spatial
#define KTOT  1152        // 128*9 reduction
#define NKT   36          // K-tiles of 32
#define MTOT  (NB * HW_ * HW_)   // 100352 output pixels

static constexpr size_t XP_ELEMS = (size_t)NB * HP * HP * CI;   // 13,776,896
static constexpr size_t WT_ELEMS = (size_t)CO * KTOT;           // 294,912
static constexpr size_t XP_BYTES = XP_ELEMS * 2;
static constexpr size_t WT_BYTES = WT_ELEMS * 2;

typedef __attribute__((ext_vector_type(8))) short bf16x8;
typedef __attribute__((ext_vector_type(4))) float f32x4;

__device__ __forceinline__ short f32_to_bf16(float f) {
  uint32_t u = __float_as_uint(f);
  uint32_t r = (u + 0x7FFFu + ((u >> 16) & 1u)) >> 16;
  return (short)r;
}

typedef __attribute__((address_space(3))) void       lds_void;
typedef const __attribute__((address_space(1))) void gbl_void;

__device__ __forceinline__ void gload16(const void* g, void* l) {
  // dest = wave-uniform LDS base; HW writes lane's 16B at base + lane*16
  __builtin_amdgcn_global_load_lds((gbl_void*)g, (lds_void*)l, 16, 0, 0);
}

// ---------------- pre-pass: x NCHW f32 -> padded NHWC bf16 ----------------
__global__ void pad_convert(const float* __restrict__ x, short* __restrict__ xp) {
  __shared__ float lds[CI][57];
  const int blk = blockIdx.x;    // NB*HP
  const int hp  = blk % HP;
  const int nb  = blk / HP;
  const int tid = threadIdx.x;   // 256
  const bool interior = (hp >= 1 && hp <= HW_);
  if (interior) {
    const float* src = x + (size_t)nb * CI * HW_ * HW_ + (size_t)(hp - 1) * HW_;
    for (int t = tid; t < CI * HW_; t += 256) {
      int c = t / HW_, w = t % HW_;
      lds[c][w] = src[(size_t)c * HW_ * HW_ + w];
    }
  }
  __syncthreads();
  short* dst = xp + (size_t)(nb * HP + hp) * HP * CI;
  for (int t = tid; t < HP * CI; t += 256) {
    int wp = t >> 7, c = t & 127;
    float v = 0.f;
    if (interior && wp >= 1 && wp <= HW_) v = lds[c][wp - 1];
    dst[t] = f32_to_bf16(v);
  }
}

// ---------------- pre-pass: weight OIHW f32 -> [o][kh][kw][c] bf16 ----------------
__global__ void wt_convert(const float* __restrict__ wt, short* __restrict__ wbT) {
  int idx = blockIdx.x * 256 + threadIdx.x;       // WT_ELEMS total, exact
  int c  = idx & 127;
  int t  = idx >> 7;          // o*9 + kh*3 + kw
  int kw = t % 3;  int t2 = t / 3;
  int kh = t2 % 3; int o  = t2 / 3;
  wbT[idx] = f32_to_bf16(wt[(((size_t)o * CI + c) * 3 + kh) * 3 + kw]);
}

// scalar byte offset into an xp pixel row for K-tile u (tap + channel-quarter)
__device__ __forceinline__ int stage_aoff(int u) {
  const int tap = u >> 2;            // 0..8
  const int cq  = u & 3;             // channel quarter (32 ch)
  const int kh  = tap / 3, kw = tap - kh * 3;
  return ((kh * HP + kw) * CI + cq * 32) * 2;
}

// ---------------- main: implicit GEMM, 256x256 tile, BK=32, 8 waves ----------------
// 4 LDS buffers x 32KB (A 16K + B 16K) = 128 KB, tiles rotate mod 4.
// Stage 3 tiles ahead; 2 phases/K-tile (16 MFMA each); frag ds_reads issued one
// phase ahead so their LDS service overlaps the MFMA cluster; barrier+sched_barrier
// per phase; setprio(1) around MFMA; vmcnt(4) per tile boundary (vmcnt(0) at v=33).
// T2 swizzle: LDS slot (row,pc) holds global piece pc^((row>>1)&3) (both-sides).
__global__ __launch_bounds__(512, 2) void conv_gemm(
    const short* __restrict__ xp, const short* __restrict__ wbT,
    const float* __restrict__ bias, float* __restrict__ out) {
  __shared__ __align__(16) char lds_[4 * 32768];

  const int tid = threadIdx.x;     // 512
  const int l   = tid & 63;
  const int wv  = tid >> 6;        // 0..7
  const int wm  = wv >> 2;         // 0..1  (m half: 128 rows)
  const int wn  = wv & 3;          // 0..3  (oc quarter: 64 cols)

  const int bid = blockIdx.x;                 // 392 = 8*49
  const int mt  = (bid & 7) * 49 + (bid >> 3);  // XCD-aware swizzle (bijective)

  // ---- staging source pointers (pre-swizzled per rule #21) ----
  // piece p = g*512 + tid ; row = p>>2 ; pc = p&3 ; src piece' = pc ^ ((row>>1)&3)
  const int pcs = (((tid & 3) ^ ((tid >> 3) & 3)) << 4);   // same for g=0 and g=1
  const char *aSrc0, *aSrc1;
  {
    int r0 = tid >> 2, r1 = 128 + (tid >> 2);
    int m0 = mt * 256 + r0, m1 = mt * 256 + r1;
    int nb0 = m0 / 3136, hw0 = m0 - nb0 * 3136, h0 = hw0 / HW_, w0 = hw0 - (hw0 / HW_) * HW_;
    int nb1 = m1 / 3136, hw1 = m1 - nb1 * 3136, h1 = hw1 / HW_, w1 = hw1 - (hw1 / HW_) * HW_;
    aSrc0 = (const char*)xp + ((size_t)((nb0 * HP + h0) * HP + w0) * CI) * 2 + pcs;
    aSrc1 = (const char*)xp + ((size_t)((nb1 * HP + h1) * HP + w1) * CI) * 2 + pcs;
  }
  const char* bSrc0 = (const char*)wbT + (size_t)(tid >> 2) * KTOT * 2 + pcs;
  const char* bSrc1 = (const char*)wbT + (size_t)(128 + (tid >> 2)) * KTOT * 2 + pcs;

  // ---- frag read lane offsets (swizzled) ----
  const int lm   = l & 15;
  const int koff = (((l >> 4) ^ ((l >> 1) & 3)) << 4);
  const int raOff = (wm * 128 + lm) * 64 + koff;   // + g*1024 (+4096 for m-frags 4-7)
  const int rbOff = (wn * 64 + lm) * 64 + koff;    // + h*1024

#define STAGE_HALF(U, G)                                                     \
  {                                                                          \
    char* dA_ = lds_ + ((U) & 3) * 32768 + (G) * 8192 + wv * 1024;           \
    gload16(aSrc##G + stage_aoff(U), dA_);                                   \
    gload16(bSrc##G + (size_t)(U) * 64, dA_ + 16384);                        \
  }

  f32x4 acc[8][4];
#pragma unroll
  for (int g = 0; g < 8; ++g)
#pragma unroll
    for (int h = 0; h < 4; ++h) acc[g][h] = {0.f, 0.f, 0.f, 0.f};

  // ---- prologue: stage tiles 0,1,2; confirm 0,1; preload tile-0 frags ----
  STAGE_HALF(0, 0) STAGE_HALF(0, 1)
  STAGE_HALF(1, 0) STAGE_HALF(1, 1)
  STAGE_HALF(2, 0) STAGE_HALF(2, 1)
  asm volatile("s_waitcnt vmcnt(4)" ::: "memory");   // tiles 0,1 landed
  __builtin_amdgcn_s_barrier();
  __builtin_amdgcn_sched_barrier(0);

  bf16x8 afA[4], afB[4], bfP[4], bfQ[4];
  {
    const char* bA_ = lds_;                // tile 0 buffer
#pragma unroll
    for (int g = 0; g < 4; ++g) afA[g] = *(const bf16x8*)(bA_ + raOff + g * 1024);
#pragma unroll
    for (int h = 0; h < 4; ++h) bfP[h] = *(const bf16x8*)(bA_ + 16384 + rbOff + h * 1024);
  }

#define TILE_(V, BFC, BFN)                                                   \
  {                                                                          \
    const int v_ = (V);                                                      \
    /* -------- phase 0: MFMA m0-3 x oc0-3 of tile v -------- */             \
    if (v_ + 3 < NKT) STAGE_HALF(v_ + 3, 0)                                  \
    { const char* bA_ = lds_ + (v_ & 3) * 32768;                             \
      _Pragma("unroll") for (int g = 0; g < 4; ++g)                          \
        afB[g] = *(const bf16x8*)(bA_ + raOff + 4096 + g * 1024); }          \
    __builtin_amdgcn_s_barrier();                                            \
    __builtin_amdgcn_sched_barrier(0);                                       \
    __builtin_amdgcn_s_setprio(1);                                           \
    _Pragma("unroll") for (int g = 0; g < 4; ++g)                            \
      _Pragma("unroll") for (int h = 0; h < 4; ++h)                          \
        acc[g][h] = __builtin_amdgcn_mfma_f32_16x16x32_bf16(                 \
            BFC[h], afA[g], acc[g][h], 0, 0, 0);                             \
    __builtin_amdgcn_s_setprio(0);                                           \
    __builtin_amdgcn_sched_barrier(0);                                       \
    /* -------- phase 1: MFMA m4-7 x oc0-3 of tile v -------- */             \
    if (v_ + 3 < NKT) STAGE_HALF(v_ + 3, 1)                                  \
    if (v_ + 1 < NKT) {                                                      \
      const char* bA_ = lds_ + ((v_ + 1) & 3) * 32768;                       \
      _Pragma("unroll") for (int g = 0; g < 4; ++g)                          \
        afA[g] = *(const bf16x8*)(bA_ + raOff + g * 1024);                   \
      _Pragma("unroll") for (int h = 0; h < 4; ++h)                          \
        BFN[h] = *(const bf16x8*)(bA_ + 16384 + rbOff + h * 1024);           \
    }                                                                        \
    if (v_ <= NKT - 4)      { asm volatile("s_waitcnt vmcnt(4)" ::: "memory"); } \
    else if (v_ == NKT - 3) { asm volatile("s_waitcnt vmcnt(0)" ::: "memory"); } \
    __builtin_amdgcn_s_barrier();                                            \
    __builtin_amdgcn_sched_barrier(0);                                       \
    __builtin_amdgcn_s_setprio(1);                                           \
    _Pragma("unroll") for (int g = 0; g < 4; ++g)                            \
      _Pragma("unroll") for (int h = 0; h < 4; ++h)                          \
        acc[4 + g][h] = __builtin_amdgcn_mfma_f32_16x16x32_bf16(             \
            BFC[h], afB[g], acc[4 + g][h], 0, 0, 0);                         \
    __builtin_amdgcn_s_setprio(0);                                           \
    __builtin_amdgcn_sched_barrier(0);                                       \
  }

  for (int t = 0; t < NKT / 2; ++t) {
    TILE_(2 * t,     bfP, bfQ)
    TILE_(2 * t + 1, bfQ, bfP)
  }
#undef TILE_
#undef STAGE_HALF

  // ---- epilogue: D rows = oc, cols = m (swapped operands) -> coalesced stores ----
  const int mBase = mt * 256 + wm * 128 + lm;
  const int ocB   = wn * 64 + (l >> 4) * 4;
  float bv[4][4];
#pragma unroll
  for (int h = 0; h < 4; ++h)
#pragma unroll
    for (int j = 0; j < 4; ++j) bv[h][j] = bias[ocB + h * 16 + j];
#pragma unroll
  for (int g = 0; g < 8; ++g) {
    const int m  = mBase + g * 16;
    const int nb = m / 3136;
    const int hw = m - nb * 3136;
    float* op = out + (size_t)nb * CO * 3136 + hw;
#pragma unroll
    for (int h = 0; h < 4; ++h) {
      const int oc = ocB + h * 16;
#pragma unroll
      for (int j = 0; j < 4; ++j)
        op[(size_t)(oc + j) * 3136] = acc[g][h][j] + bv[h][j];
    }
  }
}

// ---------------- fallback (ws too small): naive direct conv ----------------
__global__ void conv_naive(const float* __restrict__ x, const float* __restrict__ wt,
                           const float* __restrict__ bias, float* __restrict__ out) {
  const int idx = blockIdx.x * 256 + threadIdx.x;
  if (idx >= NB * CO * 3136) return;
  const int w  = idx % HW_;
  const int h  = (idx / HW_) % HW_;
  const int oc = (idx / 3136) % CO;
  const int nb = idx / (3136 * CO);
  float s = bias[oc];
  for (int c = 0; c < CI; ++c)
    for (int kh = 0; kh < 3; ++kh) {
      const int ih = h + kh - 1;
      if (ih < 0 || ih >= HW_) continue;
      for (int kw = 0; kw < 3; ++kw) {
        const int iw = w + kw - 1;
        if (iw < 0 || iw >= HW_) continue;
        s += x[((size_t)(nb * CI + c) * HW_ + ih) * HW_ + iw] *
             wt[(((size_t)oc * CI + c) * 3 + kh) * 3 + kw];
      }
    }
  out[idx] = s;
}

extern "C" void kernel_launch(void* const* d_in, const int* in_sizes, int n_in,
                              void* d_out, int out_size, void* d_ws, size_t ws_size,
                              hipStream_t stream) {
  const float* x    = (const float*)d_in[0];
  const float* wt   = (const float*)d_in[1];
  const float* bias = (const float*)d_in[2];
  float* out        = (float*)d_out;

  if (ws_size < XP_BYTES + WT_BYTES) {
    conv_naive<<<(NB * CO * 3136 + 255) / 256, 256, 0, stream>>>(x, wt, bias, out);
    return;
  }

  short* xp  = (short*)d_ws;
  short* wbT = (short*)((char*)d_ws + XP_BYTES);

  pad_convert<<<NB * HP, 256, 0, stream>>>(x, xp);
  wt_convert<<<(int)(WT_ELEMS / 256), 256, 0, stream>>>(wt, wbT);
  conv_gemm<<<MTOT / 256, 512, 0, stream>>>(xp, wbT, bias, out);
}

// Round 4
// 94.209 us; speedup vs baseline: 1.2391x; 1.0299x over previous
//
#include <hip/hip_runtime.h>
#include <cstdint>
#include <cstddef>

// ---------------- problem constants ----------------
#define NB    32          // batch
#define CI    128         // in channels
#define CO    256         // out channels
#define HW_   56          // spatial
#define HP    58          // padded spatial
#define KTOT  1152        // 128*9 reduction
#define NKT   36          // K-tiles of 32
#define MTOT  (NB * HW_ * HW_)   // 100352 output pixels

static constexpr size_t XP_ELEMS = (size_t)NB * HP * HP * CI;   // 13,776,896
static constexpr size_t WT_ELEMS = (size_t)CO * KTOT;           // 294,912
static constexpr size_t XP_BYTES = XP_ELEMS * 2;
static constexpr size_t WT_BYTES = WT_ELEMS * 2;

typedef __attribute__((ext_vector_type(8))) short bf16x8;
typedef __attribute__((ext_vector_type(4))) float f32x4;

__device__ __forceinline__ short f32_to_bf16(float f) {
  uint32_t u = __float_as_uint(f);
  uint32_t r = (u + 0x7FFFu + ((u >> 16) & 1u)) >> 16;
  return (short)r;
}

typedef __attribute__((address_space(3))) void       lds_void;
typedef const __attribute__((address_space(1))) void gbl_void;

__device__ __forceinline__ void gload16(const void* g, void* l) {
  // dest = wave-uniform LDS base; HW writes lane's 16B at base + lane*16
  __builtin_amdgcn_global_load_lds((gbl_void*)g, (lds_void*)l, 16, 0, 0);
}

// ---- pre-pass: x NCHW f32 -> padded NHWC bf16; wt OIHW -> [o][kh][kw][c] bf16 ----
__global__ void pad_convert(const float* __restrict__ x, short* __restrict__ xp,
                            const float* __restrict__ wt, short* __restrict__ wbT) {
  __shared__ float lds[CI][57];
  const int blk = blockIdx.x;    // NB*HP = 1856
  const int hp  = blk % HP;
  const int nb  = blk / HP;
  const int tid = threadIdx.x;   // 256

  // fold weight conversion into the first 1152 blocks (1152*256 == WT_ELEMS)
  if (blk < 1152) {
    int idx = blk * 256 + tid;
    int c  = idx & 127;
    int t  = idx >> 7;          // o*9 + kh*3 + kw
    int kw = t % 3;  int t2 = t / 3;
    int kh = t2 % 3; int o  = t2 / 3;
    wbT[idx] = f32_to_bf16(wt[(((size_t)o * CI + c) * 3 + kh) * 3 + kw]);
  }

  const bool interior = (hp >= 1 && hp <= HW_);
  if (interior) {
    const float* src = x + (size_t)nb * CI * HW_ * HW_ + (size_t)(hp - 1) * HW_;
    for (int t = tid; t < CI * HW_; t += 256) {
      int c = t / HW_, w = t - (t / HW_) * HW_;
      lds[c][w] = src[(size_t)c * HW_ * HW_ + w];
    }
  }
  __syncthreads();
  // vectorized store side: short4 per item (G13)
  short* dst = xp + (size_t)(nb * HP + hp) * HP * CI;
  for (int t = tid; t < HP * CI / 4; t += 256) {
    const int wp = t >> 5;          // 32 channel-quads per wp
    const int c4 = (t & 31) * 4;
    short4 s;
    if (interior && wp >= 1 && wp <= HW_) {
      s.x = f32_to_bf16(lds[c4 + 0][wp - 1]);
      s.y = f32_to_bf16(lds[c4 + 1][wp - 1]);
      s.z = f32_to_bf16(lds[c4 + 2][wp - 1]);
      s.w = f32_to_bf16(lds[c4 + 3][wp - 1]);
    } else {
      s.x = s.y = s.z = s.w = 0;
    }
    *(short4*)(dst + t * 4) = s;
  }
}

// scalar byte offset into an xp pixel row for K-tile u (tap + channel-quarter)
__device__ __forceinline__ int stage_aoff(int u) {
  const int tap = u >> 2;            // 0..8
  const int cq  = u & 3;             // channel quarter (32 ch)
  const int kh  = tap / 3, kw = tap - kh * 3;
  return ((kh * HP + kw) * CI + cq * 32) * 2;
}

// ---------------- main: implicit GEMM, 256x128 tile, BK=32, 4 waves ----------------
// Per-wave output 128m x 64oc (42.7 FLOP/LDS-byte). 3 LDS buffers x 24KB
// (A 256x32 bf16 = 16K + B 128x32 bf16 = 8K) = 72KB -> 2 blocks/CU (TLP fills
// barrier/latency stalls across desynced blocks). Stage-ahead 2 tiles, 6
// gload16/thread/tile; one boundary per K-tile: vmcnt(6) (confirms tile v+1),
// vmcnt(0) only at v=NKT-2. T2 swizzle: LDS slot (row,pc) holds global piece
// pc ^ ((row>>1)&3); applied both-sides (pre-swizzled gload source + swizzled
// ds_read) per rule #21 -- verified 0 bank conflicts in R3.
__global__ __launch_bounds__(256, 2) void conv_gemm(
    const short* __restrict__ xp, const short* __restrict__ wbT,
    const float* __restrict__ bias, float* __restrict__ out) {
  __shared__ __align__(16) char lds_[3 * 24576];

  const int tid = threadIdx.x;     // 256
  const int l   = tid & 63;
  const int wv  = tid >> 6;        // 0..3
  const int wm  = wv >> 1;         // 0..1  (m half: 128 rows)
  const int wn  = wv & 1;          // 0..1  (oc half: 64 cols)

  // grid 784 = 8 XCDs x 98; chunked bijective swizzle, nt inner (A reuse in L2)
  const int bid = blockIdx.x;
  const int lin = (bid & 7) * 98 + (bid >> 3);
  const int mt  = lin >> 1;
  const int nt  = lin & 1;

  // ---- staging source pointers (pre-swizzled per rule #21) ----
  // gload g covers rows 64g+16wv+(l>>2); lane piece (l&3); src piece = (l&3)^((l>>3)&3)
  const int pcs = (((l & 3) ^ ((l >> 3) & 3)) << 4);   // byte offset of swizzled piece
  const int srow = 16 * wv + (l >> 2);                 // 0..63 per gload group
  const char *aSrc0, *aSrc1, *aSrc2, *aSrc3;
  {
#pragma unroll
    for (int g = 0; g < 4; ++g) {
      int m  = mt * 256 + 64 * g + srow;
      int nb = m / 3136, hw = m - nb * 3136;
      int h = hw / HW_, w = hw - (hw / HW_) * HW_;
      const char* p = (const char*)xp + ((size_t)((nb * HP + h) * HP + w) * CI) * 2 + pcs;
      if (g == 0) aSrc0 = p; else if (g == 1) aSrc1 = p;
      else if (g == 2) aSrc2 = p; else aSrc3 = p;
    }
  }
  const char* bSrc0 = (const char*)wbT + (size_t)(nt * 128 +      srow) * KTOT * 2 + pcs;
  const char* bSrc1 = (const char*)wbT + (size_t)(nt * 128 + 64 + srow) * KTOT * 2 + pcs;

  // ---- frag read lane offsets (swizzled koff) ----
  const int lm   = l & 15;
  const int koff = (((l >> 4) ^ ((l >> 1) & 3)) << 4);
  const int raOff = (wm * 128 + lm) * 64 + koff;   // + g*1024, g=0..7
  const int rbOff = (wn * 64 + lm) * 64 + koff;    // + h*1024, h=0..3 (B region +16384)

  char* B0 = lds_;
  char* B1 = lds_ + 24576;
  char* B2 = lds_ + 49152;

#define STAGE(U, BUF)                                                        \
  {                                                                          \
    const int ao_ = stage_aoff(U);                                           \
    const int bo_ = (U) * 64;                                                \
    gload16(aSrc0 + ao_, (BUF) +         wv * 1024);                         \
    gload16(aSrc1 + ao_, (BUF) +  4096 + wv * 1024);                         \
    gload16(aSrc2 + ao_, (BUF) +  8192 + wv * 1024);                         \
    gload16(aSrc3 + ao_, (BUF) + 12288 + wv * 1024);                         \
    gload16(bSrc0 + bo_, (BUF) + 16384 + wv * 1024);                         \
    gload16(bSrc1 + bo_, (BUF) + 20480 + wv * 1024);                         \
  }

  f32x4 acc[8][4];
#pragma unroll
  for (int g = 0; g < 8; ++g)
#pragma unroll
    for (int h = 0; h < 4; ++h) acc[g][h] = {0.f, 0.f, 0.f, 0.f};

  // ---- prologue: stage tiles 0,1; confirm tile 0 ----
  STAGE(0, B0)
  STAGE(1, B1)
  asm volatile("s_waitcnt vmcnt(6)" ::: "memory");   // tile 0 landed
  __builtin_amdgcn_s_barrier();
  __builtin_amdgcn_sched_barrier(0);

#define TILE_BODY(V, CUR, STG)                                               \
  {                                                                          \
    const int v_ = (V);                                                      \
    if (v_ + 2 < NKT) STAGE(v_ + 2, STG)                                     \
    bf16x8 af[8], bf[4];                                                     \
    _Pragma("unroll") for (int g = 0; g < 8; ++g)                            \
        af[g] = *(const bf16x8*)((CUR) + raOff + g * 1024);                  \
    _Pragma("unroll") for (int h = 0; h < 4; ++h)                            \
        bf[h] = *(const bf16x8*)((CUR) + 16384 + rbOff + h * 1024);          \
    __builtin_amdgcn_s_setprio(1);                                           \
    _Pragma("unroll") for (int g = 0; g < 8; ++g)                            \
      _Pragma("unroll") for (int h = 0; h < 4; ++h)                          \
        acc[g][h] = __builtin_amdgcn_mfma_f32_16x16x32_bf16(                 \
            bf[h], af[g], acc[g][h], 0, 0, 0);                               \
    __builtin_amdgcn_s_setprio(0);                                           \
    if (v_ < NKT - 1) {                                                      \
      if (v_ == NKT - 2) { asm volatile("s_waitcnt vmcnt(0)" ::: "memory"); }\
      else               { asm volatile("s_waitcnt vmcnt(6)" ::: "memory"); }\
      __builtin_amdgcn_s_barrier();                                          \
      __builtin_amdgcn_sched_barrier(0);                                     \
    }                                                                        \
  }

  for (int v3 = 0; v3 < NKT; v3 += 3) {
    TILE_BODY(v3 + 0, B0, B2)   // tile v reads buf v%3, stages v+2 into (v+2)%3
    TILE_BODY(v3 + 1, B1, B0)
    TILE_BODY(v3 + 2, B2, B1)
  }
#undef TILE_BODY
#undef STAGE

  // ---- epilogue: D rows = oc, cols = m (swapped operands) -> coalesced stores ----
  const int mBase = mt * 256 + wm * 128 + lm;
  const int ocB   = nt * 128 + wn * 64 + (l >> 4) * 4;
  float bv[4][4];
#pragma unroll
  for (int h = 0; h < 4; ++h)
#pragma unroll
    for (int j = 0; j < 4; ++j) bv[h][j] = bias[ocB + h * 16 + j];
#pragma unroll
  for (int g = 0; g < 8; ++g) {
    const int m  = mBase + g * 16;
    const int nb = m / 3136;
    const int hw = m - nb * 3136;
    float* op = out + (size_t)nb * CO * 3136 + hw;
#pragma unroll
    for (int h = 0; h < 4; ++h) {
      const int oc = ocB + h * 16;
#pragma unroll
      for (int j = 0; j < 4; ++j)
        op[(size_t)(oc + j) * 3136] = acc[g][h][j] + bv[h][j];
    }
  }
}

// ---------------- fallback (ws too small): naive direct conv ----------------
__global__ void conv_naive(const float* __restrict__ x, const float* __restrict__ wt,
                           const float* __restrict__ bias, float* __restrict__ out) {
  const int idx = blockIdx.x * 256 + threadIdx.x;
  if (idx >= NB * CO * 3136) return;
  const int w  = idx % HW_;
  const int h  = (idx / HW_) % HW_;
  const int oc = (idx / 3136) % CO;
  const int nb = idx / (3136 * CO);
  float s = bias[oc];
  for (int c = 0; c < CI; ++c)
    for (int kh = 0; kh < 3; ++kh) {
      const int ih = h + kh - 1;
      if (ih < 0 || ih >= HW_) continue;
      for (int kw = 0; kw < 3; ++kw) {
        const int iw = w + kw - 1;
        if (iw < 0 || iw >= HW_) continue;
        s += x[((size_t)(nb * CI + c) * HW_ + ih) * HW_ + iw] *
             wt[(((size_t)oc * CI + c) * 3 + kh) * 3 + kw];
      }
    }
  out[idx] = s;
}

extern "C" void kernel_launch(void* const* d_in, const int* in_sizes, int n_in,
                              void* d_out, int out_size, void* d_ws, size_t ws_size,
                              hipStream_t stream) {
  const float* x    = (const float*)d_in[0];
  const float* wt   = (const float*)d_in[1];
  const float* bias = (const float*)d_in[2];
  float* out        = (float*)d_out;

  if (ws_size < XP_BYTES + WT_BYTES) {
    conv_naive<<<(NB * CO * 3136 + 255) / 256, 256, 0, stream>>>(x, wt, bias, out);
    return;
  }

  short* xp  = (short*)d_ws;
  short* wbT = (short*)((char*)d_ws + XP_BYTES);

  pad_convert<<<NB * HP, 256, 0, stream>>>(x, xp, wt, wbT);
  conv_gemm<<<(MTOT / 256) * 2, 256, 0, stream>>>(xp, wbT, bias, out);
}